// Round 6
// baseline (480.702 us; speedup 1.0000x reference)
//
#include <hip/hip_runtime.h>

#define BULK 2048
#define TOWER 512
#define E8D 8
#define NROWS 16384
#define LO_SCALE 2048.0f
#define LO_INV (1.0f / 2048.0f)

typedef _Float16 f16x8 __attribute__((ext_vector_type(8)));
typedef float f32x4 __attribute__((ext_vector_type(4)));

// async global->LDS, 16B per lane, dest = wave-uniform base + lane*16
#define GLOAD(g, l)                                                        \
    __builtin_amdgcn_global_load_lds(                                      \
        (const __attribute__((address_space(1))) void*)(g),                \
        (__attribute__((address_space(3))) void*)(l), 16, 0, 0)

// ---------------------------------------------------------------------------
// Weight prep: fp32 [K][N] -> transposed fp16 [N][K]; optionally lo residual
// (scaled by 2^11) for the split path.
// ---------------------------------------------------------------------------
template <bool LO>
__global__ void k_conv_transpose(const float* __restrict__ in, int K, int N,
                                 _Float16* __restrict__ out_hi,
                                 _Float16* __restrict__ out_lo) {
    __shared__ float tile[32][33];
    int tx = threadIdx.x & 31, ty = threadIdx.x >> 5;  // 32 x 8
    int k0 = blockIdx.x * 32, n0 = blockIdx.y * 32;
#pragma unroll
    for (int i = 0; i < 32; i += 8)
        tile[ty + i][tx] = in[(size_t)(k0 + ty + i) * N + (n0 + tx)];
    __syncthreads();
#pragma unroll
    for (int i = 0; i < 32; i += 8) {
        int n = n0 + ty + i, k = k0 + tx;
        float v = tile[tx][ty + i];
        _Float16 h = (_Float16)v;
        out_hi[(size_t)n * K + k] = h;
        if constexpr (LO)
            out_lo[(size_t)n * K + k] = (_Float16)((v - (float)h) * LO_SCALE);
    }
}

// ---------------------------------------------------------------------------
// GEMM, double-buffered single-barrier K-loop, 128x128 tile, BK=32, 4 waves.
// MODE 0: A fp32 staged RAW via global_load_lds with XOR-swizzled source
//         (slot^row&7 -> swizzled ds_read is 2-way/free), converted to hi/lo
//         fp16 in-register after ds_read. B hi/lo fp16 [N][K] via gload.
//         3 MFMA passes (hh + hl + lh), error ~2^-22 — quantizer-safe.
// MODE 1: A fp16 [M][K], B fp16 [N][K], 1 MFMA pass (decode GEMM, feeds LN).
// ---------------------------------------------------------------------------
template <int MODE>
__global__ __launch_bounds__(256, 2) void k_gemm_split(
    const float* __restrict__ Af, const _Float16* __restrict__ Ah,
    const _Float16* __restrict__ Bh, const _Float16* __restrict__ Bl,
    float* __restrict__ C, int K, int N) {
    // LDS carve: MODE0 = A-f32 32KB + B(h,l) 32KB; MODE1 = A,B f16 32KB.
    constexpr size_t LDSA_BYTES = (MODE == 0) ? 32768 : 0;
    __shared__ char ldsraw[LDSA_BYTES + 32768];
    float (*ldsA)[128][32] = (float(*)[128][32])ldsraw;            // [2][128][32]
    _Float16 (*ldsB)[2][128][32] =
        (_Float16(*)[2][128][32])(ldsraw + LDSA_BYTES);            // [2][2][128][32]

    const int t = threadIdx.x;
    const int m0 = blockIdx.x * 128, n0 = blockIdx.y * 128;
    const int wid = t >> 6, lane = t & 63;
    const int wr = wid >> 1, wc = wid & 1;
    const int lr = lane & 15, kg = lane >> 4;

    f32x4 acc1[4][4] = {};
    f32x4 acc2[4][4] = {};  // unused in MODE 1 (DCE'd)

    // ---- staging geometry ----
    const float* agp = nullptr;       // MODE0 A gload src (swizzled slot)
    const _Float16* bgp = nullptr;    // MODE0 B gload src (waves 2,3)
    const _Float16* gp = nullptr;     // MODE1 src
    int aw = 0;                       // MODE0: this wave stages A? (wid<2)

    if constexpr (MODE == 0) {
        aw = (wid < 2);
        // A: wave w(0,1) stages chunks c=w*8..w*8+7; chunk c = rows 8c..8c+7.
        // lane l -> row 8c+(l>>3), physical 16B-slot l&7 holds logical slot
        // (l&7)^(l>>3)  (XOR involution; read side applies same XOR).
        const int arow = (wid & 1) * 64 + (lane >> 3);  // + c*8 added per chunk
        const int aslot = (lane & 7) ^ (lane >> 3);
        agp = Af + (size_t)(m0 + arow) * K + aslot * 4;
        // B: wave 2 -> Bh, wave 3 -> Bl; 8 chunks of 16 rows.
        // lane l -> row 16c+(l>>2), 16B-slot l&3.
        const _Float16* bop = (wid == 3) ? Bl : Bh;
        bgp = bop + (size_t)(n0 + (lane >> 2)) * K + (lane & 3) * 8;
    } else {
        // wave w stages operand w>>1 (0=A,1=B), rows (w&1)*64 .. +64
        const _Float16* gop = (wid >> 1) ? Bh : Ah;
        const int r0 = ((wid >> 1) ? n0 : m0) + (wid & 1) * 64 + (lane >> 2);
        gp = gop + (size_t)r0 * K + (lane & 3) * 8;
    }

    auto stage0 = [&](int k0, int bb) {  // MODE0: all-async, 8 gloads/wave
        if (aw) {
#pragma unroll
            for (int c = 0; c < 8; ++c)
                GLOAD(agp + k0 + (size_t)(c * 8) * K,
                      &ldsA[bb][(wid & 1) * 64 + c * 8][0]);
        } else {
#pragma unroll
            for (int c = 0; c < 8; ++c)
                GLOAD(bgp + k0 + (size_t)(c * 16) * K,
                      &ldsB[bb][wid - 2][c * 16][0]);
        }
    };
    auto stage1 = [&](int k0, int bb) {  // MODE1: 4 gloads/wave
#pragma unroll
        for (int j = 0; j < 4; ++j)
            GLOAD(gp + k0 + (size_t)(j * 16) * K,
                  &ldsB[bb][wid >> 1][(wid & 1) * 64 + j * 16][0]);
    };

    // ---- prologue: stage tile 0 into buf 0 ----
    if constexpr (MODE == 0) stage0(0, 0);
    else stage1(0, 0);
    __syncthreads();

    const int nk = K / 32;
    for (int kt = 0; kt < nk; ++kt) {
        const int b = kt & 1;
        // issue next tile's loads before computing (overlap under MFMAs)
        if (kt + 1 < nk) {
            if constexpr (MODE == 0) stage0((kt + 1) * 32, b ^ 1);
            else stage1((kt + 1) * 32, b ^ 1);
        }

        if constexpr (MODE == 0) {
            f16x8 a_h[4], a_l[4], b_h[4], b_l[4];
#pragma unroll
            for (int m = 0; m < 4; ++m) {
                int r = wr * 64 + m * 16 + lr;
                // swizzled fp32 reads: logical slots 2kg, 2kg+1
                f32x4 w0 = *(const f32x4*)&ldsA[b][r][((2 * kg) ^ (r & 7)) * 4];
                f32x4 w1 = *(const f32x4*)&ldsA[b][r][((2 * kg + 1) ^ (r & 7)) * 4];
#pragma unroll
                for (int e = 0; e < 4; ++e) {
                    float va = w0[e], vb = w1[e];
                    _Float16 ha = (_Float16)va, hb = (_Float16)vb;
                    a_h[m][e] = ha;
                    a_h[m][e + 4] = hb;
                    a_l[m][e] = (_Float16)((va - (float)ha) * LO_SCALE);
                    a_l[m][e + 4] = (_Float16)((vb - (float)hb) * LO_SCALE);
                }
            }
#pragma unroll
            for (int n = 0; n < 4; ++n) {
                int r = wc * 64 + n * 16 + lr;
                b_h[n] = *(const f16x8*)&ldsB[b][0][r][kg * 8];
                b_l[n] = *(const f16x8*)&ldsB[b][1][r][kg * 8];
            }
#pragma unroll
            for (int m = 0; m < 4; ++m)
#pragma unroll
                for (int n = 0; n < 4; ++n) {
                    acc1[m][n] = __builtin_amdgcn_mfma_f32_16x16x32_f16(
                        a_h[m], b_h[n], acc1[m][n], 0, 0, 0);
                    acc2[m][n] = __builtin_amdgcn_mfma_f32_16x16x32_f16(
                        a_h[m], b_l[n], acc2[m][n], 0, 0, 0);
                    acc2[m][n] = __builtin_amdgcn_mfma_f32_16x16x32_f16(
                        a_l[m], b_h[n], acc2[m][n], 0, 0, 0);
                }
        } else {
            f16x8 a_h[4], b_h[4];
#pragma unroll
            for (int m = 0; m < 4; ++m) {
                int r = wr * 64 + m * 16 + lr;
                a_h[m] = *(const f16x8*)&ldsB[b][0][r][kg * 8];
            }
#pragma unroll
            for (int n = 0; n < 4; ++n) {
                int r = wc * 64 + n * 16 + lr;
                b_h[n] = *(const f16x8*)&ldsB[b][1][r][kg * 8];
            }
#pragma unroll
            for (int m = 0; m < 4; ++m)
#pragma unroll
                for (int n = 0; n < 4; ++n)
                    acc1[m][n] = __builtin_amdgcn_mfma_f32_16x16x32_f16(
                        a_h[m], b_h[n], acc1[m][n], 0, 0, 0);
        }
        __syncthreads();  // drains vmcnt(0)+lgkmcnt(0): next buf ready
    }

    // epilogue
#pragma unroll
    for (int m = 0; m < 4; ++m)
#pragma unroll
        for (int n = 0; n < 4; ++n)
#pragma unroll
            for (int i = 0; i < 4; ++i) {
                int row = m0 + wr * 64 + m * 16 + kg * 4 + i;
                int col = n0 + wc * 64 + n * 16 + lr;
                float v = acc1[m][n][i];
                if constexpr (MODE == 0) v += acc2[m][n][i] * LO_INV;
                C[(size_t)row * N + col] = v;
            }
}

// ---------------------------------------------------------------------------
// E8 lattice quantizer (faithful to the reference, fp32 scalar per lane)
// ---------------------------------------------------------------------------
__device__ inline void nearest_d8(const float* x, float* f) {
    float s = 0.f;
#pragma unroll
    for (int j = 0; j < 8; ++j) {
        f[j] = rintf(x[j]);  // round-half-even == jnp.round
        s += f[j];
    }
    float besta = -1.f, beste = 0.f;
    int bidx = 0;
#pragma unroll
    for (int j = 0; j < 8; ++j) {
        float e = x[j] - f[j];
        float a = fabsf(e);
        if (a > besta) { besta = a; beste = e; bidx = j; }  // first max kept
    }
    if (fmodf(s, 2.0f) != 0.0f) {
        float adj = (beste >= 0.f) ? 1.f : -1.f;
#pragma unroll
        for (int j = 0; j < 8; ++j) f[j] += (j == bidx) ? adj : 0.f;
    }
}

__device__ inline void nearest_e8(const float* x, float* out) {
    float fa[8], xs[8], fb[8];
    nearest_d8(x, fa);
#pragma unroll
    for (int j = 0; j < 8; ++j) xs[j] = x[j] - 0.5f;
    nearest_d8(xs, fb);
#pragma unroll
    for (int j = 0; j < 8; ++j) fb[j] += 0.5f;
    float da = 0.f, db = 0.f;
#pragma unroll
    for (int j = 0; j < 8; ++j) {
        float ea = x[j] - fa[j], eb = x[j] - fb[j];
        da += ea * ea;
        db += eb * eb;
    }
    bool pa = (da <= db);
#pragma unroll
    for (int j = 0; j < 8; ++j) out[j] = pa ? fa[j] : fb[j];
}

__device__ inline float wred64(float v) {
#pragma unroll
    for (int off = 1; off < 64; off <<= 1) v += __shfl_xor(v, off, 64);
    return v;
}

// ---------------------------------------------------------------------------
// Fused middle: LN(512) -> proj 512->8 -> rmsnorm -> residual E8 quantize
// (lane-redundant, same wave latency as 1 lane) -> decode 8->512 -> LN ->
// t2 fp16. One wave per row.
// ---------------------------------------------------------------------------
__global__ __launch_bounds__(256) void k_mid(
    const float* __restrict__ pre1, const float* __restrict__ b_bt,
    const float* __restrict__ g_et, const float* __restrict__ be_et,
    const float* __restrict__ W_t8, const float* __restrict__ b_t8,
    const float* __restrict__ rms_g, const float* __restrict__ W_8t,
    const float* __restrict__ b_8t, const float* __restrict__ g_dt,
    const float* __restrict__ b_dt, _Float16* __restrict__ t2h) {
    int wid = threadIdx.x >> 6, lane = threadIdx.x & 63;
    int row = blockIdx.x * 4 + wid;
    int cb = lane * 8;

    const float* src = pre1 + (size_t)row * TOWER + cb;
    float v[8];
    *(float4*)&v[0] = *(const float4*)(src);
    *(float4*)&v[4] = *(const float4*)(src + 4);
#pragma unroll
    for (int i = 0; i < 8; ++i) v[i] += b_bt[cb + i];

    // LN over 512
    float s = 0.f;
#pragma unroll
    for (int i = 0; i < 8; ++i) s += v[i];
    s = wred64(s);
    float mu = s * (1.f / 512.f);
    float ss = 0.f;
#pragma unroll
    for (int i = 0; i < 8; ++i) { float d = v[i] - mu; ss += d * d; }
    ss = wred64(ss);
    float inv = 1.f / sqrtf(ss * (1.f / 512.f) + 1e-6f);
    float tw[8];
#pragma unroll
    for (int i = 0; i < 8; ++i)
        tw[i] = (v[i] - mu) * inv * g_et[cb + i] + be_et[cb + i];

    // project 512 -> 8 (after wred64 every lane holds the full 8-vector)
    float p[8] = {0.f, 0.f, 0.f, 0.f, 0.f, 0.f, 0.f, 0.f};
#pragma unroll
    for (int i = 0; i < 8; ++i) {
        const float* wr_ = W_t8 + (size_t)(cb + i) * 8;
#pragma unroll
        for (int j = 0; j < 8; ++j) p[j] += tw[i] * wr_[j];
    }
#pragma unroll
    for (int j = 0; j < 8; ++j) p[j] = wred64(p[j]);

    float e8[8];
    float ms = 0.f;
#pragma unroll
    for (int j = 0; j < 8; ++j) {
        e8[j] = p[j] + b_t8[j];
        ms += e8[j] * e8[j];
    }
    float rms = sqrtf(ms * (1.f / 8.f) + 1e-6f);
#pragma unroll
    for (int j = 0; j < 8; ++j) e8[j] = e8[j] / rms * rms_g[j];

    // residual E8 quantize (all lanes redundantly -> identical q)
    float q[8] = {0.f, 0.f, 0.f, 0.f, 0.f, 0.f, 0.f, 0.f};
    float r[8];
#pragma unroll
    for (int j = 0; j < 8; ++j) r[j] = e8[j];
#pragma unroll
    for (int lvl = 0; lvl < 8; ++lvl) {
        float ql[8];
        nearest_e8(r, ql);
#pragma unroll
        for (int j = 0; j < 8; ++j) { q[j] += ql[j]; r[j] -= ql[j]; }
    }

    // decode 8 -> 512
    float o[8];
#pragma unroll
    for (int i = 0; i < 8; ++i) {
        int c = cb + i;
        float acc = b_8t[c];
#pragma unroll
        for (int j = 0; j < 8; ++j) acc += q[j] * W_8t[(size_t)j * TOWER + c];
        o[i] = acc;
    }
    // LN over 512
    float s2 = 0.f;
#pragma unroll
    for (int i = 0; i < 8; ++i) s2 += o[i];
    s2 = wred64(s2);
    float mu2 = s2 * (1.f / 512.f);
    float ss2 = 0.f;
#pragma unroll
    for (int i = 0; i < 8; ++i) { float d = o[i] - mu2; ss2 += d * d; }
    ss2 = wred64(ss2);
    float inv2 = 1.f / sqrtf(ss2 * (1.f / 512.f) + 1e-6f);

    f16x8 hv;
#pragma unroll
    for (int i = 0; i < 8; ++i) {
        int c = cb + i;
        float t2v = (o[i] - mu2) * inv2 * g_dt[c] + b_dt[c];
        hv[i] = (_Float16)t2v;
    }
    *(f16x8*)(t2h + (size_t)row * TOWER + cb) = hv;
}

// ---------------------------------------------------------------------------
// Final LN over 2048, in place on d_out (which holds t2 @ W_tb).
// ---------------------------------------------------------------------------
__global__ __launch_bounds__(256) void k_ln2(float* __restrict__ out,
                                             const float* __restrict__ b_tb,
                                             const float* __restrict__ g,
                                             const float* __restrict__ b) {
    __shared__ float red[4];
    int t = threadIdx.x, wid = t >> 6, lane = t & 63;
    size_t base = (size_t)blockIdx.x * BULK;
    int cb = t * 8;
    float v[8];
    *(float4*)&v[0] = *(const float4*)(out + base + cb);
    *(float4*)&v[4] = *(const float4*)(out + base + cb + 4);
#pragma unroll
    for (int i = 0; i < 8; ++i) v[i] += b_tb[cb + i];

    float s = 0.f;
#pragma unroll
    for (int i = 0; i < 8; ++i) s += v[i];
    s = wred64(s);
    if (lane == 0) red[wid] = s;
    __syncthreads();
    float tot = red[0] + red[1] + red[2] + red[3];
    float mu = tot * (1.f / 2048.f);
    __syncthreads();
    float ss = 0.f;
#pragma unroll
    for (int i = 0; i < 8; ++i) { float d = v[i] - mu; ss += d * d; }
    ss = wred64(ss);
    if (lane == 0) red[wid] = ss;
    __syncthreads();
    float vtot = red[0] + red[1] + red[2] + red[3];
    float inv = 1.f / sqrtf(vtot * (1.f / 2048.f) + 1e-6f);
#pragma unroll
    for (int i = 0; i < 8; ++i) v[i] = (v[i] - mu) * inv * g[cb + i] + b[cb + i];
    *(float4*)(out + base + cb) = *(float4*)&v[0];
    *(float4*)(out + base + cb + 4) = *(float4*)&v[4];
}

// ---------------------------------------------------------------------------
extern "C" void kernel_launch(void* const* d_in, const int* in_sizes, int n_in,
                              void* d_out, int out_size, void* d_ws,
                              size_t ws_size, hipStream_t stream) {
    const float* x     = (const float*)d_in[0];
    const float* W_bt  = (const float*)d_in[1];
    const float* b_bt  = (const float*)d_in[2];
    const float* g_et  = (const float*)d_in[3];
    const float* be_et = (const float*)d_in[4];
    const float* W_t8  = (const float*)d_in[5];
    const float* b_t8  = (const float*)d_in[6];
    const float* rms_g = (const float*)d_in[7];
    const float* W_8t  = (const float*)d_in[8];
    const float* b_8t  = (const float*)d_in[9];
    const float* g_dt  = (const float*)d_in[10];
    const float* b_dt  = (const float*)d_in[11];
    const float* W_tb  = (const float*)d_in[12];
    const float* b_tb  = (const float*)d_in[13];
    const float* g_db  = (const float*)d_in[14];
    const float* b_db  = (const float*)d_in[15];
    float* out = (float*)d_out;

    // Workspace (22 MB)
    char* w = (char*)d_ws;
    _Float16* Wbt_h = (_Float16*)w; w += (size_t)BULK * TOWER * 2;
    _Float16* Wbt_l = (_Float16*)w; w += (size_t)BULK * TOWER * 2;
    _Float16* Wtb_h = (_Float16*)w; w += (size_t)TOWER * BULK * 2;
    _Float16* t2h   = (_Float16*)w; w += (size_t)NROWS * TOWER * 2;
    // pre1 (32 MB) lives in d_out (128 MB); fully overwritten by GEMM2 later.
    float* pre1 = out;

    // weight prep
    k_conv_transpose<true><<<dim3(BULK / 32, TOWER / 32), 256, 0, stream>>>(
        W_bt, BULK, TOWER, Wbt_h, Wbt_l);
    k_conv_transpose<false><<<dim3(TOWER / 32, BULK / 32), 256, 0, stream>>>(
        W_tb, TOWER, BULK, Wtb_h, nullptr);

    // encode GEMM (3-pass split fp16, all-async staging): pre1 = x @ W_bt
    k_gemm_split<0><<<dim3(NROWS / 128, TOWER / 128), 256, 0, stream>>>(
        x, nullptr, Wbt_h, Wbt_l, pre1, BULK, TOWER);

    // fused middle: LN -> proj8 -> rms -> E8 RVQ -> decode -> LN -> t2 fp16
    k_mid<<<NROWS / 4, 256, 0, stream>>>(pre1, b_bt, g_et, be_et, W_t8, b_t8,
                                         rms_g, W_8t, b_8t, g_dt, b_dt, t2h);

    // decode GEMM (single-pass fp16): d_out = t2 @ W_tb (pre-LN)
    k_gemm_split<1><<<dim3(NROWS / 128, BULK / 128), 256, 0, stream>>>(
        nullptr, t2h, Wtb_h, nullptr, out, TOWER, BULK);

    // final LN in place
    k_ln2<<<NROWS, 256, 0, stream>>>(out, b_tb, g_db, b_db);
}